// Round 1
// baseline (221.424 us; speedup 1.0000x reference)
//
#include <hip/hip_runtime.h>

// GraphConvolution: out[b,n,o] = sum_m adj[n,m] * (F[b,m,:] . W[o,:]) + bias[o]
// B=8192, N=4, DIN=1024, DOUT=256. Strategy: G = F_bf16 @ W_bf16^T via MFMA
// (16x16x32 bf16), adj 4x4 mix applied per-lane on fp32 accumulators in the
// epilogue (C/D layout: row = (lane>>4)*4 + reg -> one batch per lane).

#define DIN 1024
#define DOUT 256
#define BM 128
#define BK 64
#define KI 16                      // DIN / BK
#define LDB 72                     // padded row stride in bf16 (2-way-free banks)
#define WS_PER_KB (DOUT * LDB)     // 18432 ushorts per K-block image
#define A_HALFS (BM * LDB)         // 9216
#define B_HALFS (DOUT * LDB)       // 18432

typedef __bf16 bf16x8 __attribute__((ext_vector_type(8)));
typedef float f32x4 __attribute__((ext_vector_type(4)));
typedef unsigned short u16x8 __attribute__((ext_vector_type(8)));

__device__ __forceinline__ unsigned short f2bf(float f) {
  union { float f; unsigned int u; } v;
  v.f = f;
  unsigned int u = v.u;
  u += 0x7fffu + ((u >> 16) & 1u);   // round-to-nearest-even
  return (unsigned short)(u >> 16);
}

__device__ __forceinline__ void glds16(const unsigned short* g, unsigned short* l) {
  __builtin_amdgcn_global_load_lds(
      (const __attribute__((address_space(1))) void*)g,
      (__attribute__((address_space(3))) void*)l, 16, 0, 0);
}

// Pre-kernel: W [256x1024] fp32 -> bf16 ws image [kb][col][72] (64 data + 8 pad),
// byte-identical to the LDS B-tile so global_load_lds can stage it directly.
__global__ __launch_bounds__(256) void wprep_kernel(
    const float* __restrict__ W, unsigned short* __restrict__ ws) {
  const int t = blockIdx.x * 256 + threadIdx.x;  // 32768 threads
  const int col = t >> 7;                        // 0..255
  const int k8 = t & 127;                        // 8-float chunk within K
  const int kb = k8 >> 3;
  const int kc = (k8 & 7) * 8;
  const f32x4* src = (const f32x4*)(W + (size_t)col * DIN + k8 * 8);
  f32x4 a = src[0], b = src[1];
  u16x8 pk;
#pragma unroll
  for (int m = 0; m < 4; ++m) {
    pk[m] = f2bf(a[m]);
    pk[4 + m] = f2bf(b[m]);
  }
  unsigned short* dst = ws + (size_t)kb * WS_PER_KB + col * LDB + kc;
  *(u16x8*)dst = pk;
  if ((k8 & 7) == 7) {  // one thread per (col,kb) zero-fills the 8-bf16 pad
    u16x8 z = {0, 0, 0, 0, 0, 0, 0, 0};
    *(u16x8*)(ws + (size_t)kb * WS_PER_KB + col * LDB + 64) = z;
  }
}

__global__ __launch_bounds__(512, 2) void gconv_kernel(
    const float* __restrict__ adj, const float* __restrict__ feat,
    const unsigned short* __restrict__ wbf, const float* __restrict__ bias,
    float* __restrict__ out) {
  __shared__ __align__(16) unsigned short sB[B_HALFS];  // [col][LDB]
  __shared__ __align__(16) unsigned short sA[A_HALFS];  // [row][LDB]
  __shared__ float sbias[DOUT];

  const int tid = threadIdx.x;
  const int bM = blockIdx.x * BM;

  if (tid < DOUT) sbias[tid] = bias[tid];

  // A staging: thread handles 16-B chunks tid and tid+512 of the 128x64 tile
  const int row0 = tid >> 3;
  const int kc0 = (tid & 7) * 8;
  const int row1 = (tid + 512) >> 3;
  const float* aptr0 = feat + (size_t)(bM + row0) * DIN + kc0;
  const float* aptr1 = feat + (size_t)(bM + row1) * DIN + kc0;
  unsigned short* sAw0 = sA + row0 * LDB + kc0;
  unsigned short* sAw1 = sA + row1 * LDB + kc0;

  // wave coords: 2x4 wave grid, 64 rows x 64 cols per wave
  const int lane = tid & 63;
  const int wid = tid >> 6;
  const int wr = (wid >> 2) * 64;
  const int wc = (wid & 3) * 64;
  const int rl = lane & 15;
  const int q = lane >> 4;

  f32x4 acc[4][4];
#pragma unroll
  for (int i = 0; i < 4; ++i)
#pragma unroll
    for (int j = 0; j < 4; ++j) acc[i][j] = f32x4{0.f, 0.f, 0.f, 0.f};

  // prologue: prefetch A tile kb=0 into regs
  f32x4 pa0 = *(const f32x4*)aptr0;
  f32x4 pa1 = *(const f32x4*)(aptr0 + 4);
  f32x4 pa2 = *(const f32x4*)aptr1;
  f32x4 pa3 = *(const f32x4*)(aptr1 + 4);
  aptr0 += BK;
  aptr1 += BK;

  for (int kb = 0; kb < KI; ++kb) {
    // stage B (pre-converted bf16, padded image) straight into LDS
    const unsigned short* bs = wbf + (size_t)kb * WS_PER_KB;
#pragma unroll
    for (int r = 0; r < 4; ++r) {
      const int idx = r * 512 + tid;
      glds16(bs + idx * 8, sB + idx * 8);
    }
    if (tid < 256) {
      const int idx = 2048 + tid;
      glds16(bs + idx * 8, sB + idx * 8);
    }

    // convert current A regs to bf16
    u16x8 pk0, pk1;
#pragma unroll
    for (int m = 0; m < 4; ++m) {
      pk0[m] = f2bf(pa0[m]);
      pk0[4 + m] = f2bf(pa1[m]);
      pk1[m] = f2bf(pa2[m]);
      pk1[4 + m] = f2bf(pa3[m]);
    }
    // prefetch next A tile into regs (overlaps with this iter's barrier wait)
    if (kb + 1 < KI) {
      pa0 = *(const f32x4*)aptr0;
      pa1 = *(const f32x4*)(aptr0 + 4);
      pa2 = *(const f32x4*)aptr1;
      pa3 = *(const f32x4*)(aptr1 + 4);
      aptr0 += BK;
      aptr1 += BK;
    }
    *(u16x8*)sAw0 = pk0;
    *(u16x8*)sAw1 = pk1;
    __syncthreads();

#pragma unroll
    for (int ks = 0; ks < 2; ++ks) {
      const int ko = ks * 32 + q * 8;
      bf16x8 af[4], bfr[4];
#pragma unroll
      for (int i = 0; i < 4; ++i)
        af[i] = *(const bf16x8*)(sA + (wr + i * 16 + rl) * LDB + ko);
#pragma unroll
      for (int j = 0; j < 4; ++j)
        bfr[j] = *(const bf16x8*)(sB + (wc + j * 16 + rl) * LDB + ko);
#pragma unroll
      for (int i = 0; i < 4; ++i)
#pragma unroll
        for (int j = 0; j < 4; ++j)
          acc[i][j] = __builtin_amdgcn_mfma_f32_16x16x32_bf16(af[i], bfr[j],
                                                              acc[i][j], 0, 0, 0);
    }
    __syncthreads();
  }

  // epilogue: adj 4x4 mix (intra-lane: regs = rows 4q..4q+3) + bias, fp32 store
  float am[16];
#pragma unroll
  for (int i = 0; i < 16; ++i) am[i] = adj[i];  // uniform -> scalar loads

  float bv[4];
#pragma unroll
  for (int j = 0; j < 4; ++j) bv[j] = sbias[wc + j * 16 + rl];

#pragma unroll
  for (int i = 0; i < 4; ++i) {
    const size_t rowbase = (size_t)(bM + wr + i * 16 + q * 4);
#pragma unroll
    for (int j = 0; j < 4; ++j) {
      const int col = wc + j * 16 + rl;
      float* op = out + rowbase * DOUT + col;
      f32x4 g = acc[i][j];
#pragma unroll
      for (int n = 0; n < 4; ++n) {
        op[(size_t)n * DOUT] = am[n * 4 + 0] * g[0] + am[n * 4 + 1] * g[1] +
                               am[n * 4 + 2] * g[2] + am[n * 4 + 3] * g[3] +
                               bv[j];
      }
    }
  }
}

extern "C" void kernel_launch(void* const* d_in, const int* in_sizes, int n_in,
                              void* d_out, int out_size, void* d_ws,
                              size_t ws_size, hipStream_t stream) {
  const float* adj = (const float*)d_in[0];
  const float* feat = (const float*)d_in[1];
  const float* W = (const float*)d_in[2];
  const float* bias = (const float*)d_in[3];
  float* out = (float*)d_out;
  unsigned short* ws = (unsigned short*)d_ws;  // needs 16*36864 B = 576 KiB

  wprep_kernel<<<128, 256, 0, stream>>>(W, ws);
  gconv_kernel<<<8192 * 4 / BM, 512, 0, stream>>>(adj, feat, ws, bias, out);
}

// Round 2
// 219.024 us; speedup vs baseline: 1.0110x; 1.0110x over previous
//
#include <hip/hip_runtime.h>

// GraphConvolution: out[b,n,o] = sum_m adj[n,m] * (F[b,m,:] . W[o,:]) + b[o]
// B=8192, N=4, DIN=1024, DOUT=256. G = F_bf16 @ W_bf16^T via MFMA 16x16x32,
// adj 4x4 mix applied per-lane on fp32 accumulators in the epilogue
// (C/D layout: row = (lane>>4)*4 + reg -> 4 rows of one batch live in one lane).
// R2: BM 128->64, 256 threads, grid 512 = 2 blocks/CU so cross-block wave
// overlap hides the per-iteration barrier/vmcnt drain (1 block/CU can't).

#define DIN 1024
#define DOUT 256
#define BM 64
#define BK 64
#define KI 16                      // DIN / BK
#define LDB 72                     // padded row stride in bf16 (16B-multiple)
#define WS_PER_KB (DOUT * LDB)     // 18432 ushorts per K-block image
#define A_HALFS (BM * LDB)         // 4608
#define B_HALFS (DOUT * LDB)       // 18432

typedef __bf16 bf16x8 __attribute__((ext_vector_type(8)));
typedef float f32x4 __attribute__((ext_vector_type(4)));
typedef unsigned short u16x8 __attribute__((ext_vector_type(8)));

__device__ __forceinline__ unsigned short f2bf(float f) {
  union { float f; unsigned int u; } v;
  v.f = f;
  unsigned int u = v.u;
  u += 0x7fffu + ((u >> 16) & 1u);   // round-to-nearest-even
  return (unsigned short)(u >> 16);
}

__device__ __forceinline__ void glds16(const unsigned short* g, unsigned short* l) {
  __builtin_amdgcn_global_load_lds(
      (const __attribute__((address_space(1))) void*)g,
      (__attribute__((address_space(3))) void*)l, 16, 0, 0);
}

// Pre-kernel: W [256x1024] fp32 -> bf16 ws image [kb][col][72] (64 data + 8 pad),
// byte-identical to the LDS B-tile so global_load_lds can stage it directly.
__global__ __launch_bounds__(256) void wprep_kernel(
    const float* __restrict__ W, unsigned short* __restrict__ ws) {
  const int t = blockIdx.x * 256 + threadIdx.x;  // 32768 threads
  const int col = t >> 7;                        // 0..255
  const int k8 = t & 127;                        // 8-float chunk within K
  const int kb = k8 >> 3;
  const int kc = (k8 & 7) * 8;
  const f32x4* src = (const f32x4*)(W + (size_t)col * DIN + k8 * 8);
  f32x4 a = src[0], b = src[1];
  u16x8 pk;
#pragma unroll
  for (int m = 0; m < 4; ++m) {
    pk[m] = f2bf(a[m]);
    pk[4 + m] = f2bf(b[m]);
  }
  unsigned short* dst = ws + (size_t)kb * WS_PER_KB + col * LDB + kc;
  *(u16x8*)dst = pk;
  if ((k8 & 7) == 7) {  // one thread per (col,kb) zero-fills the 8-bf16 pad
    u16x8 z = {0, 0, 0, 0, 0, 0, 0, 0};
    *(u16x8*)(ws + (size_t)kb * WS_PER_KB + col * LDB + 64) = z;
  }
}

__global__ __launch_bounds__(256, 2) void gconv_kernel(
    const float* __restrict__ adj, const float* __restrict__ feat,
    const unsigned short* __restrict__ wbf, const float* __restrict__ bias,
    float* __restrict__ out) {
  __shared__ __align__(16) unsigned short sB[B_HALFS];  // [col][LDB]
  __shared__ __align__(16) unsigned short sA[A_HALFS];  // [row][LDB]
  __shared__ float sbias[DOUT];

  const int tid = threadIdx.x;
  const int bM = blockIdx.x * BM;

  sbias[tid] = bias[tid];

  // A staging: thread handles 32-B chunks tid and tid+256 of the 64x64 tile
  const int row0 = tid >> 3;          // 0..31
  const int kc0 = (tid & 7) * 8;
  const int row1 = (tid + 256) >> 3;  // 32..63
  const float* aptr0 = feat + (size_t)(bM + row0) * DIN + kc0;
  const float* aptr1 = feat + (size_t)(bM + row1) * DIN + kc0;
  unsigned short* sAw0 = sA + row0 * LDB + kc0;
  unsigned short* sAw1 = sA + row1 * LDB + kc0;

  // wave coords: 1x4 wave grid, 64 rows x 64 cols per wave
  const int lane = tid & 63;
  const int wid = tid >> 6;
  const int wc = wid * 64;
  const int rl = lane & 15;
  const int q = lane >> 4;

  f32x4 acc[4][4];
#pragma unroll
  for (int i = 0; i < 4; ++i)
#pragma unroll
    for (int j = 0; j < 4; ++j) acc[i][j] = f32x4{0.f, 0.f, 0.f, 0.f};

  // prologue: prefetch A tile kb=0 into regs
  f32x4 pa0 = *(const f32x4*)aptr0;
  f32x4 pa1 = *(const f32x4*)(aptr0 + 4);
  f32x4 pa2 = *(const f32x4*)aptr1;
  f32x4 pa3 = *(const f32x4*)(aptr1 + 4);
  aptr0 += BK;
  aptr1 += BK;

  for (int kb = 0; kb < KI; ++kb) {
    // stage B (pre-converted bf16, padded image) straight into LDS
    const unsigned short* bs = wbf + (size_t)kb * WS_PER_KB;
#pragma unroll
    for (int r = 0; r < 9; ++r) {  // 2304 16-B chunks / 256 threads
      const int idx = r * 256 + tid;
      glds16(bs + idx * 8, sB + idx * 8);
    }

    // convert current A regs to bf16
    u16x8 pk0, pk1;
#pragma unroll
    for (int m = 0; m < 4; ++m) {
      pk0[m] = f2bf(pa0[m]);
      pk0[4 + m] = f2bf(pa1[m]);
      pk1[m] = f2bf(pa2[m]);
      pk1[4 + m] = f2bf(pa3[m]);
    }
    // prefetch next A tile into regs (overlaps with this iter's barrier wait)
    if (kb + 1 < KI) {
      pa0 = *(const f32x4*)aptr0;
      pa1 = *(const f32x4*)(aptr0 + 4);
      pa2 = *(const f32x4*)aptr1;
      pa3 = *(const f32x4*)(aptr1 + 4);
      aptr0 += BK;
      aptr1 += BK;
    }
    *(u16x8*)sAw0 = pk0;
    *(u16x8*)sAw1 = pk1;
    __syncthreads();

#pragma unroll
    for (int ks = 0; ks < 2; ++ks) {
      const int ko = ks * 32 + q * 8;
      bf16x8 af[4], bfr[4];
#pragma unroll
      for (int i = 0; i < 4; ++i)
        af[i] = *(const bf16x8*)(sA + (i * 16 + rl) * LDB + ko);
#pragma unroll
      for (int j = 0; j < 4; ++j)
        bfr[j] = *(const bf16x8*)(sB + (wc + j * 16 + rl) * LDB + ko);
#pragma unroll
      for (int i = 0; i < 4; ++i)
#pragma unroll
        for (int j = 0; j < 4; ++j)
          acc[i][j] = __builtin_amdgcn_mfma_f32_16x16x32_bf16(af[i], bfr[j],
                                                              acc[i][j], 0, 0, 0);
    }
    __syncthreads();
  }

  // epilogue: adj 4x4 mix (intra-lane: regs = rows 4q..4q+3) + bias, fp32 store
  float am[16];
#pragma unroll
  for (int i = 0; i < 16; ++i) am[i] = adj[i];  // uniform -> scalar loads

  float bv[4];
#pragma unroll
  for (int j = 0; j < 4; ++j) bv[j] = sbias[wc + j * 16 + rl];

#pragma unroll
  for (int i = 0; i < 4; ++i) {
    const size_t rowbase = (size_t)(bM + i * 16 + q * 4);
#pragma unroll
    for (int j = 0; j < 4; ++j) {
      const int col = wc + j * 16 + rl;
      float* op = out + rowbase * DOUT + col;
      f32x4 g = acc[i][j];
#pragma unroll
      for (int n = 0; n < 4; ++n) {
        op[(size_t)n * DOUT] = am[n * 4 + 0] * g[0] + am[n * 4 + 1] * g[1] +
                               am[n * 4 + 2] * g[2] + am[n * 4 + 3] * g[3] +
                               bv[j];
      }
    }
  }
}

extern "C" void kernel_launch(void* const* d_in, const int* in_sizes, int n_in,
                              void* d_out, int out_size, void* d_ws,
                              size_t ws_size, hipStream_t stream) {
  const float* adj = (const float*)d_in[0];
  const float* feat = (const float*)d_in[1];
  const float* W = (const float*)d_in[2];
  const float* bias = (const float*)d_in[3];
  float* out = (float*)d_out;
  unsigned short* ws = (unsigned short*)d_ws;  // needs 16*36864*2 B = 1.18 MB

  wprep_kernel<<<128, 256, 0, stream>>>(W, ws);
  gconv_kernel<<<8192 * 4 / BM, 256, 0, stream>>>(adj, feat, ws, bias, out);
}